// Round 4
// baseline (1245.610 us; speedup 1.0000x reference)
//
#include <hip/hip_runtime.h>
#include <hip/hip_bf16.h>

#define NN 50000
#define NE 800000
#define DD 256
#define EPSV 1e-5f

typedef float f32x4 __attribute__((ext_vector_type(4)));
typedef short bf16x8s __attribute__((ext_vector_type(8)));
typedef unsigned int uint32;

__device__ __forceinline__ float lo16f(uint32 u) {  // low ushort as bf16
  return __builtin_bit_cast(float, u << 16);
}
__device__ __forceinline__ float hi16f(uint32 u) {  // high ushort as bf16
  return __builtin_bit_cast(float, u & 0xffff0000u);
}
__device__ __forceinline__ float bf2f(unsigned int u16v) {
  return __builtin_bit_cast(float, u16v << 16);
}
__device__ __forceinline__ unsigned short f2bf(float f) {
  return __builtin_bit_cast(unsigned short, __float2bfloat16(f));
}
__device__ __forceinline__ bf16x8s ld16(const unsigned short* p) {
  return *reinterpret_cast<const bf16x8s*>(p);
}
__device__ __forceinline__ void mfma_bf16(bf16x8s a, bf16x8s b, f32x4& c) {
  asm("v_mfma_f32_16x16x32_bf16 %0, %1, %2, %0" : "+v"(c) : "v"(a), "v"(b));
}

// Chunked activation layout: chunk c (16 feats), node n:
//   ushort base = (c*NN + n)*32 ; [0..15] = hi bf16 of the 16 feats, [16..31] = lo bf16.

// ---------------- CSR build (by dst) ----------------

__global__ void deg_count_k(const int* __restrict__ ei, int* __restrict__ deg) {
  int e = blockIdx.x * 256 + threadIdx.x;
  if (e < NE) atomicAdd(&deg[ei[NE + e]], 1);
}

__global__ void scan1_k(const int* __restrict__ deg, int* __restrict__ row_ptr,
                        int* __restrict__ blockSums) {
  __shared__ int s[1024];
  int gid = blockIdx.x * 1024 + threadIdx.x;
  int v = (gid < NN) ? deg[gid] : 0;
  s[threadIdx.x] = v;
  __syncthreads();
  for (int off = 1; off < 1024; off <<= 1) {
    int t = (threadIdx.x >= off) ? s[threadIdx.x - off] : 0;
    __syncthreads();
    s[threadIdx.x] += t;
    __syncthreads();
  }
  if (gid < NN) row_ptr[gid] = s[threadIdx.x] - v;
  if (threadIdx.x == 1023) blockSums[blockIdx.x] = s[1023];
}

__global__ void scan2_k(const int* __restrict__ blockSums, int* __restrict__ blockOffs,
                        int* __restrict__ row_ptr, int nblocks) {
  if (threadIdx.x == 0) {
    int run = 0;
    for (int i = 0; i < nblocks; ++i) { blockOffs[i] = run; run += blockSums[i]; }
    row_ptr[NN] = run;
  }
}

__global__ void scan3_k(int* __restrict__ row_ptr, const int* __restrict__ blockOffs,
                        const int* __restrict__ deg, float* __restrict__ deg_inv) {
  int gid = blockIdx.x * 1024 + threadIdx.x;
  if (gid < NN) {
    row_ptr[gid] += blockOffs[blockIdx.x];
    deg_inv[gid] = 1.0f / (float)max(deg[gid], 1);
  }
}

__global__ void csr_fill_k(const int* __restrict__ ei, int* __restrict__ cursor,
                           unsigned short* __restrict__ col16) {
  int e = blockIdx.x * 256 + threadIdx.x;
  if (e < NE) {
    int pos = atomicAdd(&cursor[ei[NE + e]], 1);
    col16[pos] = (unsigned short)ei[e];  // src < 50000 < 2^16
  }
}

// ---------------- x (row-major f32) -> chunked hi/lo bf16 ----------------

__global__ __launch_bounds__(256) void split_x_k(const float* __restrict__ x,
                                                 uint32* __restrict__ xc) {
  int ni = threadIdx.x & 15, c = threadIdx.x >> 4;
  int node = blockIdx.x * 16 + ni;
  const float4* xr = reinterpret_cast<const float4*>(x + (size_t)node * DD + c * 16);
  float f[16];
#pragma unroll
  for (int q = 0; q < 4; ++q) {
    float4 v = xr[q];
    f[q * 4 + 0] = v.x; f[q * 4 + 1] = v.y; f[q * 4 + 2] = v.z; f[q * 4 + 3] = v.w;
  }
  uint32 wbuf[16];
#pragma unroll
  for (int g = 0; g < 8; ++g) {
    unsigned short h0 = f2bf(f[2 * g]), h1 = f2bf(f[2 * g + 1]);
    unsigned short l0 = f2bf(f[2 * g] - bf2f(h0));
    unsigned short l1 = f2bf(f[2 * g + 1] - bf2f(h1));
    wbuf[g] = (uint32)h0 | ((uint32)h1 << 16);
    wbuf[8 + g] = (uint32)l0 | ((uint32)l1 << 16);
  }
  uint32* dst = xc + ((size_t)c * NN + node) * 16;
#pragma unroll
  for (int q = 0; q < 4; ++q)
    reinterpret_cast<uint4*>(dst)[q] =
        make_uint4(wbuf[q * 4], wbuf[q * 4 + 1], wbuf[q * 4 + 2], wbuf[q * 4 + 3]);
}

// ---------------- W (din x dout) -> W^T hi/lo bf16 planes ----------------

__global__ __launch_bounds__(256) void wtprep_k(
    const float* __restrict__ W0, const float* __restrict__ W1,
    const float* __restrict__ W2, const float* __restrict__ W3,
    const float* __restrict__ W4, const float* __restrict__ W5,
    unsigned short* __restrict__ wt) {
  int p = blockIdx.y;
  const float* W = (p == 0) ? W0 : (p == 1) ? W1 : (p == 2) ? W2
                   : (p == 3) ? W3 : (p == 4) ? W4 : W5;
  unsigned short* thi = wt + (size_t)(2 * p) * 65536;
  unsigned short* tlo = wt + (size_t)(2 * p + 1) * 65536;
  int gid = blockIdx.x * 256 + threadIdx.x;
  int n = gid >> 6, k4 = (gid & 63) << 2;
  ushort4 hi, lo;
  unsigned short* hp = &hi.x; unsigned short* lp = &lo.x;
#pragma unroll
  for (int r = 0; r < 4; ++r) {
    float v = W[(size_t)(k4 + r) * DD + n];
    unsigned short h = f2bf(v);
    hp[r] = h;
    lp[r] = f2bf(v - bf2f(h));
  }
  *reinterpret_cast<ushort4*>(thi + (size_t)n * DD + k4) = hi;
  *reinterpret_cast<ushort4*>(tlo + (size_t)n * DD + k4) = lo;
}

// ---------------- aggregation: XCD-partitioned chunks, 4 lanes/edge ----------------
// Block b -> XCD b%8 (round-robin dispatch); chunk = (b>=25000)*8 + (b&7) so each
// chunk's 3.2 MB table is resident in exactly one XCD's L2.
// 16 lanes per node: 4 edge-slots x 4 quarter-lanes (q: 0=hi f0-7,1=hi f8-15,2=lo f0-7,3=lo f8-15).

__global__ __launch_bounds__(256) void sage_agg_k(
    const uint32* __restrict__ act, const int* __restrict__ rp,
    const unsigned short* __restrict__ ci, const float* __restrict__ deg_inv,
    uint32* __restrict__ agg) {
  int b = blockIdx.x;
  int ph = (b >= 25000);
  int bb = ph ? b - 25000 : b;
  int c = ph * 8 + (bb & 7);
  int node = (bb >> 3) * 16 + (threadIdx.x >> 4);
  int g = threadIdx.x & 15;
  int s = g >> 2;   // edge slot
  int q = g & 3;    // 16B quarter of the 64B node row

  const uint4* base = reinterpret_cast<const uint4*>(act + (size_t)c * NN * 16);
  int beg = rp[node], end = rp[node + 1];

  float a[8];
#pragma unroll
  for (int i = 0; i < 8; ++i) a[i] = 0.f;

  for (int e = beg; e < end; e += 4) {
    int ee = e + s;
    if (ee < end) {
      int src = (int)__builtin_nontemporal_load(ci + ee);
      uint4 v = base[(size_t)src * 4 + q];
      a[0] += lo16f(v.x); a[1] += hi16f(v.x);
      a[2] += lo16f(v.y); a[3] += hi16f(v.y);
      a[4] += lo16f(v.z); a[5] += hi16f(v.z);
      a[6] += lo16f(v.w); a[7] += hi16f(v.w);
    }
  }
  // fold the 4 edge-slots (lane bits 2,3), then fold hi+lo planes (lane bit 1)
#pragma unroll
  for (int i = 0; i < 8; ++i) {
    a[i] += __shfl_xor(a[i], 4);
    a[i] += __shfl_xor(a[i], 8);
    a[i] += __shfl_xor(a[i], 2);
  }
  float di = deg_inv[node];
#pragma unroll
  for (int i = 0; i < 8; ++i) a[i] *= di;

  // lanes q=0/2 hold feats 0-7 totals, q=1/3 hold feats 8-15 totals (identical pairs).
  // q<2 packs the hi plane, q>=2 packs the lo plane; store lanes: s==0 only.
  uint32 wo[4];
  if (q < 2) {
#pragma unroll
    for (int i = 0; i < 4; ++i) {
      unsigned short h0 = f2bf(a[2 * i]), h1 = f2bf(a[2 * i + 1]);
      wo[i] = (uint32)h0 | ((uint32)h1 << 16);
    }
  } else {
#pragma unroll
    for (int i = 0; i < 4; ++i) {
      float t0 = a[2 * i], t1 = a[2 * i + 1];
      unsigned short l0 = f2bf(t0 - bf2f(f2bf(t0)));
      unsigned short l1 = f2bf(t1 - bf2f(f2bf(t1)));
      wo[i] = (uint32)l0 | ((uint32)l1 << 16);
    }
  }
  if (s == 0) {
    size_t u4 = ((size_t)c * NN + node) * 4 + q;
    reinterpret_cast<uint4*>(agg)[u4] = make_uint4(wo[0], wo[1], wo[2], wo[3]);
  }
}

// ---------------- MFMA GEMM: LDS-free, barrier-free ----------------
// Wave owns 32 rows x 256 cols. acc[2][16] f32x4 (128 VGPR). A streamed from the
// chunked act (hi/lo), register-prefetched 1 step; B fragments from L2-resident W^T.

template <bool DO_BN>
__global__ __launch_bounds__(256) void sage_gemm_k(
    const unsigned short* __restrict__ aggC, const unsigned short* __restrict__ hC,
    const unsigned short* __restrict__ wlHi, const unsigned short* __restrict__ wlLo,
    const unsigned short* __restrict__ wrHi, const unsigned short* __restrict__ wrLo,
    const float* __restrict__ bias,
    const float* __restrict__ gamma, const float* __restrict__ beta,
    const float* __restrict__ mean, const float* __restrict__ var,
    float* __restrict__ outF, unsigned short* __restrict__ outC) {
  int wave = threadIdx.x >> 6, lane = threadIdx.x & 63;
  int lr = lane & 15, lq = lane >> 4;
  int m0 = blockIdx.x * 128 + wave * 32;

  f32x4 acc[2][16];
#pragma unroll
  for (int r = 0; r < 2; ++r)
#pragma unroll
    for (int j = 0; j < 16; ++j) acc[r][j] = (f32x4)0.f;

  int row0 = min(m0 + 0 * 16 + lr, NN - 1);
  int row1 = min(m0 + 1 * 16 + lr, NN - 1);

  auto ldA = [&](int ks, bf16x8s* aH, bf16x8s* aL) {
    int kt = ks & 7;
    const unsigned short* A = (ks < 8) ? aggC : hC;
    int cch = kt * 2 + (lq >> 1);
    int ko = (lq & 1) * 8;
    size_t u0 = ((size_t)cch * NN + row0) * 32 + ko;
    size_t u1 = ((size_t)cch * NN + row1) * 32 + ko;
    aH[0] = ld16(A + u0); aL[0] = ld16(A + u0 + 16);
    aH[1] = ld16(A + u1); aL[1] = ld16(A + u1 + 16);
  };

  bf16x8s aH[2], aL[2], nH[2], nL[2];
  ldA(0, aH, aL);

#pragma unroll 1
  for (int ks = 0; ks < 16; ++ks) {
    if (ks < 15) ldA(ks + 1, nH, nL);  // register prefetch of next A step
    const unsigned short* Bh = (ks < 8) ? wlHi : wrHi;
    const unsigned short* Bl = (ks < 8) ? wlLo : wrLo;
    int kk = (ks & 7) * 32 + lq * 8;
#pragma unroll
    for (int j = 0; j < 16; ++j) {
      size_t ub = (size_t)(j * 16 + lr) * DD + kk;
      bf16x8s bH = ld16(Bh + ub);
      bf16x8s bL = ld16(Bl + ub);
      mfma_bf16(aH[0], bH, acc[0][j]);
      mfma_bf16(aH[0], bL, acc[0][j]);
      mfma_bf16(aL[0], bH, acc[0][j]);
      mfma_bf16(aH[1], bH, acc[1][j]);
      mfma_bf16(aH[1], bL, acc[1][j]);
      mfma_bf16(aL[1], bH, acc[1][j]);
    }
    aH[0] = nH[0]; aH[1] = nH[1]; aL[0] = nL[0]; aL[1] = nL[1];
  }

  // ---- epilogue: n-frag j == chunk j ----
#pragma unroll 1
  for (int j = 0; j < 16; ++j) {
    int n = j * 16 + lr;
    float bb = bias[n], sc = 0.f, sh = 0.f;
    if (DO_BN) {
      float sgm = gamma[n] * rsqrtf(var[n] + EPSV);
      sc = sgm;
      sh = beta[n] - mean[n] * sgm;
    }
#pragma unroll
    for (int r = 0; r < 2; ++r) {
#pragma unroll
      for (int rr = 0; rr < 4; ++rr) {
        int m = m0 + r * 16 + lq * 4 + rr;
        if (m < NN) {
          float v = acc[r][j][rr] + bb;
          if (DO_BN) {
            v = fmaxf(v * sc + sh, 0.f);
            size_t ub = ((size_t)j * NN + m) * 32;
            v += bf2f(hC[ub + lr]) + bf2f(hC[ub + 16 + lr]);  // residual
            unsigned short h = f2bf(v);
            outC[ub + lr] = h;
            outC[ub + 16 + lr] = f2bf(v - bf2f(h));
          } else {
            outF[(size_t)m * DD + n] = v;
          }
        }
      }
    }
  }
}

// ---------------- launch ----------------

extern "C" void kernel_launch(void* const* d_in, const int* in_sizes, int n_in,
                              void* d_out, int out_size, void* d_ws, size_t ws_size,
                              hipStream_t stream) {
  const float* x   = (const float*)d_in[0];
  const int*   ei  = (const int*)d_in[1];
  const float* Wl[3] = {(const float*)d_in[2], (const float*)d_in[5], (const float*)d_in[8]};
  const float* Wr[3] = {(const float*)d_in[3], (const float*)d_in[6], (const float*)d_in[9]};
  const float* bs[3] = {(const float*)d_in[4], (const float*)d_in[7], (const float*)d_in[10]};
  const float* g0  = (const float*)d_in[11];
  const float* be0 = (const float*)d_in[12];
  const float* mu0 = (const float*)d_in[13];
  const float* va0 = (const float*)d_in[14];
  const float* g1  = (const float*)d_in[15];
  const float* be1 = (const float*)d_in[16];
  const float* mu1 = (const float*)d_in[17];
  const float* va1 = (const float*)d_in[18];
  float* out = (float*)d_out;

  char* w = (char*)d_ws;
  const size_t o_deg    = 0;            // NN ints
  const size_t o_rowptr = 262144;       // NN+1 ints
  const size_t o_cursor = 524288;       // NN ints
  const size_t o_col16  = 786432;       // NE u16 = 1.6 MB
  const size_t o_deginv = 2621440;      // NN f32
  const size_t o_bsum   = 2883584;
  const size_t o_boff   = 2887680;
  const size_t o_wt     = 2891776;      // 12 planes * 131072 B = 1.57 MB
  const size_t ACT      = (size_t)16 * NN * 64;  // 51.2 MB chunked buffer
  const size_t o_xC     = 6291456;
  const size_t o_h1C    = o_xC + ACT;
  const size_t o_aggC   = o_xC + 2 * ACT;        // end ~159.9 MB

  int*   deg     = (int*)(w + o_deg);
  int*   row_ptr = (int*)(w + o_rowptr);
  int*   cursor  = (int*)(w + o_cursor);
  unsigned short* col16 = (unsigned short*)(w + o_col16);
  float* deg_inv = (float*)(w + o_deginv);
  int*   bsum    = (int*)(w + o_bsum);
  int*   boff    = (int*)(w + o_boff);
  unsigned short* wt = (unsigned short*)(w + o_wt);
  uint32* xC   = (uint32*)(w + o_xC);
  uint32* h1C  = (uint32*)(w + o_h1C);
  uint32* aggC = (uint32*)(w + o_aggC);

  unsigned short* wlT[3][2];
  unsigned short* wrT[3][2];
  for (int l = 0; l < 3; ++l) {
    wlT[l][0] = wt + (size_t)(4 * l + 0) * 65536;
    wlT[l][1] = wt + (size_t)(4 * l + 1) * 65536;
    wrT[l][0] = wt + (size_t)(4 * l + 2) * 65536;
    wrT[l][1] = wt + (size_t)(4 * l + 3) * 65536;
  }

  const int SCAN_BLOCKS = (NN + 1023) / 1024;  // 49

  // ---- CSR build ----
  hipMemsetAsync(deg, 0, NN * sizeof(int), stream);
  deg_count_k<<<NE / 256, 256, 0, stream>>>(ei, deg);
  scan1_k<<<SCAN_BLOCKS, 1024, 0, stream>>>(deg, row_ptr, bsum);
  scan2_k<<<1, 64, 0, stream>>>(bsum, boff, row_ptr, SCAN_BLOCKS);
  scan3_k<<<SCAN_BLOCKS, 1024, 0, stream>>>(row_ptr, boff, deg, deg_inv);
  hipMemcpyAsync(cursor, row_ptr, NN * sizeof(int), hipMemcpyDeviceToDevice, stream);
  csr_fill_k<<<NE / 256, 256, 0, stream>>>(ei, cursor, col16);

  // ---- precompute chunked x and W^T planes ----
  split_x_k<<<NN / 16, 256, 0, stream>>>(x, xC);
  wtprep_k<<<dim3(64, 6), 256, 0, stream>>>(Wl[0], Wr[0], Wl[1], Wr[1], Wl[2], Wr[2], wt);

  const int AGRID = 50000;            // 16 chunks * 3125 node-groups, XCD-partitioned
  dim3 ggrid((NN + 127) / 128);       // 391

  // ---- layer 0: x -> h1 ----
  sage_agg_k<<<AGRID, 256, 0, stream>>>(xC, row_ptr, col16, deg_inv, aggC);
  sage_gemm_k<true><<<ggrid, 256, 0, stream>>>(
      (const unsigned short*)aggC, (const unsigned short*)xC,
      wlT[0][0], wlT[0][1], wrT[0][0], wrT[0][1],
      bs[0], g0, be0, mu0, va0, nullptr, (unsigned short*)h1C);
  // ---- layer 1: h1 -> h2 (into xC) ----
  sage_agg_k<<<AGRID, 256, 0, stream>>>(h1C, row_ptr, col16, deg_inv, aggC);
  sage_gemm_k<true><<<ggrid, 256, 0, stream>>>(
      (const unsigned short*)aggC, (const unsigned short*)h1C,
      wlT[1][0], wlT[1][1], wrT[1][0], wrT[1][1],
      bs[1], g1, be1, mu1, va1, nullptr, (unsigned short*)xC);
  // ---- layer 2: h2 -> out (fp32) ----
  sage_agg_k<<<AGRID, 256, 0, stream>>>(xC, row_ptr, col16, deg_inv, aggC);
  sage_gemm_k<false><<<ggrid, 256, 0, stream>>>(
      (const unsigned short*)aggC, (const unsigned short*)xC,
      wlT[2][0], wlT[2][1], wrT[2][0], wrT[2][1],
      bs[2], nullptr, nullptr, nullptr, nullptr, out, nullptr);
}

// Round 5
// 936.784 us; speedup vs baseline: 1.3297x; 1.3297x over previous
//
#include <hip/hip_runtime.h>
#include <hip/hip_bf16.h>

#define NN 50000
#define NE 800000
#define DD 256
#define EPSV 1e-5f

typedef float f32x4 __attribute__((ext_vector_type(4)));
typedef short bf16x8s __attribute__((ext_vector_type(8)));
typedef unsigned int uint32;

__device__ __forceinline__ float lo16f(uint32 u) {
  return __builtin_bit_cast(float, u << 16);
}
__device__ __forceinline__ float hi16f(uint32 u) {
  return __builtin_bit_cast(float, u & 0xffff0000u);
}
__device__ __forceinline__ float bf2f(unsigned int u16v) {
  return __builtin_bit_cast(float, u16v << 16);
}
__device__ __forceinline__ unsigned short f2bf(float f) {
  return __builtin_bit_cast(unsigned short, __float2bfloat16(f));
}
__device__ __forceinline__ void mfma_bf16(bf16x8s a, bf16x8s b, f32x4& c) {
  asm("v_mfma_f32_16x16x32_bf16 %0, %1, %2, %0" : "+v"(c) : "v"(a), "v"(b));
}
__device__ __forceinline__ void gload_lds16(const void* g, void* l) {
  __builtin_amdgcn_global_load_lds((const __attribute__((address_space(1))) void*)g,
                                   (__attribute__((address_space(3))) void*)l, 16, 0, 0);
}

// Chunked activation layout: chunk c (16 feats), node n:
//   ushort base = (c*NN + n)*32 ; [0..15]=hi bf16 of 16 feats, [16..31]=lo bf16.

// ---------------- CSR build (by dst) ----------------

__global__ void deg_count_k(const int* __restrict__ ei, int* __restrict__ deg) {
  int e = blockIdx.x * 256 + threadIdx.x;
  if (e < NE) atomicAdd(&deg[ei[NE + e]], 1);
}

__global__ void scan1_k(const int* __restrict__ deg, int* __restrict__ row_ptr,
                        int* __restrict__ blockSums) {
  __shared__ int s[1024];
  int gid = blockIdx.x * 1024 + threadIdx.x;
  int v = (gid < NN) ? deg[gid] : 0;
  s[threadIdx.x] = v;
  __syncthreads();
  for (int off = 1; off < 1024; off <<= 1) {
    int t = (threadIdx.x >= off) ? s[threadIdx.x - off] : 0;
    __syncthreads();
    s[threadIdx.x] += t;
    __syncthreads();
  }
  if (gid < NN) row_ptr[gid] = s[threadIdx.x] - v;
  if (threadIdx.x == 1023) blockSums[blockIdx.x] = s[1023];
}

__global__ void scan2_k(const int* __restrict__ blockSums, int* __restrict__ blockOffs,
                        int* __restrict__ row_ptr, int nblocks) {
  if (threadIdx.x == 0) {
    int run = 0;
    for (int i = 0; i < nblocks; ++i) { blockOffs[i] = run; run += blockSums[i]; }
    row_ptr[NN] = run;
  }
}

__global__ void scan3_k(int* __restrict__ row_ptr, const int* __restrict__ blockOffs,
                        const int* __restrict__ deg, float* __restrict__ deg_inv) {
  int gid = blockIdx.x * 1024 + threadIdx.x;
  if (gid < NN) {
    row_ptr[gid] += blockOffs[blockIdx.x];
    deg_inv[gid] = 1.0f / (float)max(deg[gid], 1);
  }
}

__global__ void csr_fill_k(const int* __restrict__ ei, int* __restrict__ cursor,
                           unsigned short* __restrict__ col16) {
  int e = blockIdx.x * 256 + threadIdx.x;
  if (e < NE) {
    int pos = atomicAdd(&cursor[ei[NE + e]], 1);
    col16[pos] = (unsigned short)ei[e];
  }
}

// ---------------- x (row-major f32) -> chunked hi/lo bf16 ----------------

__global__ __launch_bounds__(256) void split_x_k(const float* __restrict__ x,
                                                 uint32* __restrict__ xc) {
  int ni = threadIdx.x & 15, c = threadIdx.x >> 4;
  int node = blockIdx.x * 16 + ni;
  const float4* xr = reinterpret_cast<const float4*>(x + (size_t)node * DD + c * 16);
  float f[16];
#pragma unroll
  for (int qq = 0; qq < 4; ++qq) {
    float4 v = xr[qq];
    f[qq * 4 + 0] = v.x; f[qq * 4 + 1] = v.y; f[qq * 4 + 2] = v.z; f[qq * 4 + 3] = v.w;
  }
  uint32 wbuf[16];
#pragma unroll
  for (int g = 0; g < 8; ++g) {
    unsigned short h0 = f2bf(f[2 * g]), h1 = f2bf(f[2 * g + 1]);
    unsigned short l0 = f2bf(f[2 * g] - bf2f(h0));
    unsigned short l1 = f2bf(f[2 * g + 1] - bf2f(h1));
    wbuf[g] = (uint32)h0 | ((uint32)h1 << 16);
    wbuf[8 + g] = (uint32)l0 | ((uint32)l1 << 16);
  }
  uint32* dst = xc + ((size_t)c * NN + node) * 16;
#pragma unroll
  for (int qq = 0; qq < 4; ++qq)
    reinterpret_cast<uint4*>(dst)[qq] =
        make_uint4(wbuf[qq * 4], wbuf[qq * 4 + 1], wbuf[qq * 4 + 2], wbuf[qq * 4 + 3]);
}

// ---------------- W (din x dout) -> W^T hi/lo bf16 planes ----------------

__global__ __launch_bounds__(256) void wtprep_k(
    const float* __restrict__ W0, const float* __restrict__ W1,
    const float* __restrict__ W2, const float* __restrict__ W3,
    const float* __restrict__ W4, const float* __restrict__ W5,
    unsigned short* __restrict__ wt) {
  int p = blockIdx.y;
  const float* W = (p == 0) ? W0 : (p == 1) ? W1 : (p == 2) ? W2
                   : (p == 3) ? W3 : (p == 4) ? W4 : W5;
  unsigned short* thi = wt + (size_t)(2 * p) * 65536;
  unsigned short* tlo = wt + (size_t)(2 * p + 1) * 65536;
  int gid = blockIdx.x * 256 + threadIdx.x;
  int n = gid >> 6, k4 = (gid & 63) << 2;
  ushort4 hi, lo;
  unsigned short* hp = &hi.x; unsigned short* lp = &lo.x;
#pragma unroll
  for (int r = 0; r < 4; ++r) {
    float v = W[(size_t)(k4 + r) * DD + n];
    unsigned short h = f2bf(v);
    hp[r] = h;
    lp[r] = f2bf(v - bf2f(h));
  }
  *reinterpret_cast<ushort4*>(thi + (size_t)n * DD + k4) = hi;
  *reinterpret_cast<ushort4*>(tlo + (size_t)n * DD + k4) = lo;
}

// ---------------- aggregation: XCD-partitioned chunks, 32 lanes/node ----------------
// Grid 100000: b<50000 -> chunks 0..7 (XCD b%8), else chunks 8..15. Per node:
// 8 edge-slots x 4 quarter-lanes -> 8 independent 64B gathers in flight.

__global__ __launch_bounds__(256) void sage_agg_k(
    const uint32* __restrict__ act, const int* __restrict__ rp,
    const unsigned short* __restrict__ ci, const float* __restrict__ deg_inv,
    uint32* __restrict__ agg) {
  int b = blockIdx.x;
  int ph = (b >= 50000);
  int bb = ph ? b - 50000 : b;
  int c = ph * 8 + (bb & 7);
  int node = (bb >> 3) * 8 + (threadIdx.x >> 5);
  int t5 = threadIdx.x & 31;
  int s = t5 >> 2;   // edge slot 0..7
  int q = t5 & 3;    // 16B quarter

  const uint4* base = reinterpret_cast<const uint4*>(act + (size_t)c * NN * 16);
  int beg = rp[node], end = rp[node + 1];

  float a[8];
#pragma unroll
  for (int i = 0; i < 8; ++i) a[i] = 0.f;

  for (int e = beg; e < end; e += 8) {
    int ee = e + s;
    bool valid = ee < end;
    int ec = valid ? ee : beg;
    int src = (int)ci[ec];
    uint4 v = base[(size_t)src * 4 + q];
    float msk = valid ? 1.f : 0.f;
    a[0] = fmaf(msk, lo16f(v.x), a[0]); a[1] = fmaf(msk, hi16f(v.x), a[1]);
    a[2] = fmaf(msk, lo16f(v.y), a[2]); a[3] = fmaf(msk, hi16f(v.y), a[3]);
    a[4] = fmaf(msk, lo16f(v.z), a[4]); a[5] = fmaf(msk, hi16f(v.z), a[5]);
    a[6] = fmaf(msk, lo16f(v.w), a[6]); a[7] = fmaf(msk, hi16f(v.w), a[7]);
  }
  // fold edge-slots (lane bits 2,3,4) then hi/lo planes (bit 1)
#pragma unroll
  for (int i = 0; i < 8; ++i) {
    a[i] += __shfl_xor(a[i], 4);
    a[i] += __shfl_xor(a[i], 8);
    a[i] += __shfl_xor(a[i], 16);
    a[i] += __shfl_xor(a[i], 2);
  }
  float di = deg_inv[node];
#pragma unroll
  for (int i = 0; i < 8; ++i) a[i] *= di;

  uint32 wo[4];
  if (q < 2) {
#pragma unroll
    for (int i = 0; i < 4; ++i) {
      unsigned short h0 = f2bf(a[2 * i]), h1 = f2bf(a[2 * i + 1]);
      wo[i] = (uint32)h0 | ((uint32)h1 << 16);
    }
  } else {
#pragma unroll
    for (int i = 0; i < 4; ++i) {
      float t0 = a[2 * i], t1 = a[2 * i + 1];
      unsigned short l0 = f2bf(t0 - bf2f(f2bf(t0)));
      unsigned short l1 = f2bf(t1 - bf2f(f2bf(t1)));
      wo[i] = (uint32)l0 | ((uint32)l1 << 16);
    }
  }
  if (s == 0) {
    reinterpret_cast<uint4*>(agg)[((size_t)c * NN + node) * 4 + q] =
        make_uint4(wo[0], wo[1], wo[2], wo[3]);
  }
}

// ---------------- MFMA GEMM: 64x256 tile, BK=32, 8 waves, LDS-staged ----------------
// A read exactly once. LDS 40KB: A units [sub 0..3][plane] 8x1KB, B units [j 0..15][plane] 32x1KB.
// Wave w: sub = w&3 (16 rows), h = w>>2 (col half). Epilogue: frag->LDS transpose -> 1KB stores.

template <bool DO_BN>
__global__ __launch_bounds__(512) void sage_gemm_k(
    const unsigned short* __restrict__ aggC, const unsigned short* __restrict__ hC,
    const unsigned short* __restrict__ wlHi, const unsigned short* __restrict__ wlLo,
    const unsigned short* __restrict__ wrHi, const unsigned short* __restrict__ wrLo,
    const float* __restrict__ bias,
    const float* __restrict__ gamma, const float* __restrict__ beta,
    const float* __restrict__ mean, const float* __restrict__ var,
    float* __restrict__ outF, unsigned short* __restrict__ outC) {
  __shared__ __attribute__((aligned(128))) char lds[40960];

  int tid = threadIdx.x, wave = tid >> 6, l = tid & 63;
  int lr = l & 15, q = l >> 4;
  int sub = wave & 3, h = wave >> 2;
  int m0 = blockIdx.x * 64;

  f32x4 acc[8];
#pragma unroll
  for (int j = 0; j < 8; ++j) acc[j] = (f32x4)0.f;

  int rowA = m0 + lr;  // + sub_u*16 added per unit; clamp per unit

#pragma unroll 1
  for (int t = 0; t < 16; ++t) {
    bool first = t < 8;
    const unsigned short* Ap = first ? aggC : hC;
    int t7 = t & 7;
    // ---- stage: 5 units of 1KB per wave (8 A units + 32 B units) ----
#pragma unroll
    for (int i = 0; i < 5; ++i) {
      int u = wave * 5 + i;
      if (u < 8) {
        int su = u >> 1, p = u & 1;
        int row = rowA + su * 16;
        row = row < NN ? row : NN - 1;
        int c = 2 * t7 + (q >> 1);
        gload_lds16(Ap + ((size_t)c * NN + row) * 32 + p * 16 + (q & 1) * 8,
                    &lds[u * 1024 + l * 16]);
      } else {
        int ub = u - 8, j = ub >> 1, p = ub & 1;
        const unsigned short* W = first ? (p ? wlLo : wlHi) : (p ? wrLo : wrHi);
        gload_lds16(W + (size_t)(j * 16 + lr) * DD + t7 * 32 + q * 8,
                    &lds[8192 + ub * 1024 + l * 16]);
      }
    }
    __syncthreads();
    // ---- compute: 1 m-frag x 8 n-frags x 3 products ----
    bf16x8s aH = *reinterpret_cast<const bf16x8s*>(&lds[(sub * 2 + 0) * 1024 + l * 16]);
    bf16x8s aL = *reinterpret_cast<const bf16x8s*>(&lds[(sub * 2 + 1) * 1024 + l * 16]);
#pragma unroll
    for (int jj = 0; jj < 8; ++jj) {
      int j = h * 8 + jj;
      bf16x8s bH = *reinterpret_cast<const bf16x8s*>(&lds[8192 + (j * 2 + 0) * 1024 + l * 16]);
      bf16x8s bL = *reinterpret_cast<const bf16x8s*>(&lds[8192 + (j * 2 + 1) * 1024 + l * 16]);
      mfma_bf16(aH, bH, acc[jj]);
      mfma_bf16(aH, bL, acc[jj]);
      mfma_bf16(aL, bH, acc[jj]);
    }
    __syncthreads();
  }

  if (DO_BN) {
    // ---- epilogue: 4 rounds of 64 cols; frag -> LDS(f32) -> packed 16B/thread stores ----
    float* Lf = reinterpret_cast<float*>(lds);
#pragma unroll 1
    for (int g = 0; g < 4; ++g) {
      if (h == (g >> 1)) {
#pragma unroll
        for (int jj2 = 0; jj2 < 4; ++jj2) {
          int jl = (g & 1) * 4 + jj2;
          int n = (4 * g + jj2) * 16 + lr;
          float bb = bias[n];
          float sc = gamma[n] * rsqrtf(var[n] + EPSV);
          float sh = beta[n] - mean[n] * sc;
#pragma unroll
          for (int reg = 0; reg < 4; ++reg) {
            int ml = sub * 16 + 4 * q + reg;
            Lf[ml * 68 + jj2 * 16 + lr] = fmaxf((acc[jl][reg] + bb) * sc + sh, 0.f);
          }
        }
      }
      __syncthreads();
#pragma unroll
      for (int sw = 0; sw < 2; ++sw) {
        int u = (tid >> 2) + sw * 128;
        int q4 = tid & 3;
        int ml = u & 63, cc = u >> 6;
        int c = 4 * g + cc;
        int m = m0 + ml;
        if (m < NN) {
          float v[8];
          int lb = ml * 68 + cc * 16 + (q4 & 1) * 8;
#pragma unroll
          for (int i = 0; i < 8; ++i) v[i] = Lf[lb + i];
          size_t ub4 = ((size_t)c * NN + m) * 4;  // uint4 index of the 64B unit
          const uint4* hp = reinterpret_cast<const uint4*>(hC) + ub4;
          uint4 rh = hp[q4 & 1];
          uint4 rl = hp[2 + (q4 & 1)];
          v[0] += lo16f(rh.x) + lo16f(rl.x); v[1] += hi16f(rh.x) + hi16f(rl.x);
          v[2] += lo16f(rh.y) + lo16f(rl.y); v[3] += hi16f(rh.y) + hi16f(rl.y);
          v[4] += lo16f(rh.z) + lo16f(rl.z); v[5] += hi16f(rh.z) + hi16f(rl.z);
          v[6] += lo16f(rh.w) + lo16f(rl.w); v[7] += hi16f(rh.w) + hi16f(rl.w);
          uint32 wo[4];
          if (q4 < 2) {
#pragma unroll
            for (int i = 0; i < 4; ++i) {
              unsigned short h0 = f2bf(v[2 * i]), h1 = f2bf(v[2 * i + 1]);
              wo[i] = (uint32)h0 | ((uint32)h1 << 16);
            }
          } else {
#pragma unroll
            for (int i = 0; i < 4; ++i) {
              float t0 = v[2 * i], t1 = v[2 * i + 1];
              unsigned short l0 = f2bf(t0 - bf2f(f2bf(t0)));
              unsigned short l1 = f2bf(t1 - bf2f(f2bf(t1)));
              wo[i] = (uint32)l0 | ((uint32)l1 << 16);
            }
          }
          reinterpret_cast<uint4*>(outC)[ub4 + q4] = make_uint4(wo[0], wo[1], wo[2], wo[3]);
        }
      }
      __syncthreads();
    }
  } else {
    // ---- fp32 row-major output (scalar stores; proven clean in R2) ----
#pragma unroll
    for (int jj = 0; jj < 8; ++jj) {
      int n = (h * 8 + jj) * 16 + lr;
      float bb = bias[n];
#pragma unroll
      for (int reg = 0; reg < 4; ++reg) {
        int m = m0 + sub * 16 + 4 * q + reg;
        if (m < NN) outF[(size_t)m * DD + n] = acc[jj][reg] + bb;
      }
    }
  }
}

// ---------------- launch ----------------

extern "C" void kernel_launch(void* const* d_in, const int* in_sizes, int n_in,
                              void* d_out, int out_size, void* d_ws, size_t ws_size,
                              hipStream_t stream) {
  const float* x   = (const float*)d_in[0];
  const int*   ei  = (const int*)d_in[1];
  const float* Wl[3] = {(const float*)d_in[2], (const float*)d_in[5], (const float*)d_in[8]};
  const float* Wr[3] = {(const float*)d_in[3], (const float*)d_in[6], (const float*)d_in[9]};
  const float* bs[3] = {(const float*)d_in[4], (const float*)d_in[7], (const float*)d_in[10]};
  const float* g0  = (const float*)d_in[11];
  const float* be0 = (const float*)d_in[12];
  const float* mu0 = (const float*)d_in[13];
  const float* va0 = (const float*)d_in[14];
  const float* g1  = (const float*)d_in[15];
  const float* be1 = (const float*)d_in[16];
  const float* mu1 = (const float*)d_in[17];
  const float* va1 = (const float*)d_in[18];
  float* out = (float*)d_out;

  char* w = (char*)d_ws;
  const size_t o_deg    = 0;
  const size_t o_rowptr = 262144;
  const size_t o_cursor = 524288;
  const size_t o_col16  = 786432;       // NE u16 = 1.6 MB
  const size_t o_deginv = 2621440;
  const size_t o_bsum   = 2883584;
  const size_t o_boff   = 2887680;
  const size_t o_wt     = 2891776;      // 12 planes * 131072 B
  const size_t ACT      = (size_t)16 * NN * 64;  // 51.2 MB
  const size_t o_xC     = 6291456;
  const size_t o_h1C    = o_xC + ACT;
  const size_t o_aggC   = o_xC + 2 * ACT;

  int*   deg     = (int*)(w + o_deg);
  int*   row_ptr = (int*)(w + o_rowptr);
  int*   cursor  = (int*)(w + o_cursor);
  unsigned short* col16 = (unsigned short*)(w + o_col16);
  float* deg_inv = (float*)(w + o_deginv);
  int*   bsum    = (int*)(w + o_bsum);
  int*   boff    = (int*)(w + o_boff);
  unsigned short* wt = (unsigned short*)(w + o_wt);
  uint32* xC   = (uint32*)(w + o_xC);
  uint32* h1C  = (uint32*)(w + o_h1C);
  uint32* aggC = (uint32*)(w + o_aggC);

  unsigned short* wlT[3][2];
  unsigned short* wrT[3][2];
  for (int l = 0; l < 3; ++l) {
    wlT[l][0] = wt + (size_t)(4 * l + 0) * 65536;
    wlT[l][1] = wt + (size_t)(4 * l + 1) * 65536;
    wrT[l][0] = wt + (size_t)(4 * l + 2) * 65536;
    wrT[l][1] = wt + (size_t)(4 * l + 3) * 65536;
  }

  const int SCAN_BLOCKS = (NN + 1023) / 1024;

  hipMemsetAsync(deg, 0, NN * sizeof(int), stream);
  deg_count_k<<<NE / 256, 256, 0, stream>>>(ei, deg);
  scan1_k<<<SCAN_BLOCKS, 1024, 0, stream>>>(deg, row_ptr, bsum);
  scan2_k<<<1, 64, 0, stream>>>(bsum, boff, row_ptr, SCAN_BLOCKS);
  scan3_k<<<SCAN_BLOCKS, 1024, 0, stream>>>(row_ptr, boff, deg, deg_inv);
  hipMemcpyAsync(cursor, row_ptr, NN * sizeof(int), hipMemcpyDeviceToDevice, stream);
  csr_fill_k<<<NE / 256, 256, 0, stream>>>(ei, cursor, col16);

  split_x_k<<<NN / 16, 256, 0, stream>>>(x, xC);
  wtprep_k<<<dim3(64, 6), 256, 0, stream>>>(Wl[0], Wr[0], Wl[1], Wr[1], Wl[2], Wr[2], wt);

  const int AGRID = 100000;          // 2 phases x 8 chunks x 6250 node-groups
  dim3 ggrid((NN + 63) / 64);        // 782

  // ---- layer 0: x -> h1 ----
  sage_agg_k<<<AGRID, 256, 0, stream>>>(xC, row_ptr, col16, deg_inv, aggC);
  sage_gemm_k<true><<<ggrid, 512, 0, stream>>>(
      (const unsigned short*)aggC, (const unsigned short*)xC,
      wlT[0][0], wlT[0][1], wrT[0][0], wrT[0][1],
      bs[0], g0, be0, mu0, va0, nullptr, (unsigned short*)h1C);
  // ---- layer 1: h1 -> h2 (into xC) ----
  sage_agg_k<<<AGRID, 256, 0, stream>>>(h1C, row_ptr, col16, deg_inv, aggC);
  sage_gemm_k<true><<<ggrid, 512, 0, stream>>>(
      (const unsigned short*)aggC, (const unsigned short*)h1C,
      wlT[1][0], wlT[1][1], wrT[1][0], wrT[1][1],
      bs[1], g1, be1, mu1, va1, nullptr, (unsigned short*)xC);
  // ---- layer 2: h2 -> out (fp32) ----
  sage_agg_k<<<AGRID, 256, 0, stream>>>(xC, row_ptr, col16, deg_inv, aggC);
  sage_gemm_k<false><<<ggrid, 512, 0, stream>>>(
      (const unsigned short*)aggC, (const unsigned short*)xC,
      wlT[2][0], wlT[2][1], wrT[2][0], wrT[2][1],
      bs[2], nullptr, nullptr, nullptr, nullptr, out, nullptr);
}

// Round 6
// 749.458 us; speedup vs baseline: 1.6620x; 1.2499x over previous
//
#include <hip/hip_runtime.h>
#include <hip/hip_bf16.h>

#define NN 50000
#define NE 800000
#define DD 256
#define EPSV 1e-5f

typedef float f32x4 __attribute__((ext_vector_type(4)));
typedef short bf16x8s __attribute__((ext_vector_type(8)));
typedef unsigned int uint32;
typedef uint32 u32x4 __attribute__((ext_vector_type(4)));

__device__ __forceinline__ float bf2f(unsigned int u16v) {
  return __builtin_bit_cast(float, u16v << 16);
}
__device__ __forceinline__ unsigned short f2bf(float f) {
  return __builtin_bit_cast(unsigned short, __float2bfloat16(f));
}
__device__ __forceinline__ void mfma_bf16(bf16x8s a, bf16x8s b, f32x4& c) {
  asm("v_mfma_f32_16x16x32_bf16 %0, %1, %2, %0" : "+v"(c) : "v"(a), "v"(b));
}
__device__ __forceinline__ void gload_lds16(const void* g, void* l) {
  __builtin_amdgcn_global_load_lds((const __attribute__((address_space(1))) void*)g,
                                   (__attribute__((address_space(3))) void*)l, 16, 0, 0);
}

// fp32 chunked activation layout: chunk c (16 feats), node n:
//   float base = (c*NN + n)*16 ; 16 f32 = 64 B per node-chunk.

// ---------------- CSR build (by dst) ----------------

__global__ void deg_count_k(const int* __restrict__ ei, int* __restrict__ deg) {
  int e = blockIdx.x * 256 + threadIdx.x;
  if (e < NE) atomicAdd(&deg[ei[NE + e]], 1);
}

__global__ void scan1_k(const int* __restrict__ deg, int* __restrict__ row_ptr,
                        int* __restrict__ blockSums) {
  __shared__ int s[1024];
  int gid = blockIdx.x * 1024 + threadIdx.x;
  int v = (gid < NN) ? deg[gid] : 0;
  s[threadIdx.x] = v;
  __syncthreads();
  for (int off = 1; off < 1024; off <<= 1) {
    int t = (threadIdx.x >= off) ? s[threadIdx.x - off] : 0;
    __syncthreads();
    s[threadIdx.x] += t;
    __syncthreads();
  }
  if (gid < NN) row_ptr[gid] = s[threadIdx.x] - v;
  if (threadIdx.x == 1023) blockSums[blockIdx.x] = s[1023];
}

__global__ void scan2_k(const int* __restrict__ blockSums, int* __restrict__ blockOffs,
                        int* __restrict__ row_ptr, int nblocks) {
  if (threadIdx.x == 0) {
    int run = 0;
    for (int i = 0; i < nblocks; ++i) { blockOffs[i] = run; run += blockSums[i]; }
    row_ptr[NN] = run;
  }
}

__global__ void scan3_k(int* __restrict__ row_ptr, const int* __restrict__ blockOffs,
                        const int* __restrict__ deg, float* __restrict__ deg_inv,
                        int* __restrict__ cursor) {
  int gid = blockIdx.x * 1024 + threadIdx.x;
  if (gid < NN) {
    int v = row_ptr[gid] + blockOffs[blockIdx.x];
    row_ptr[gid] = v;
    cursor[gid] = v;
    deg_inv[gid] = 1.0f / (float)max(deg[gid], 1);
  }
}

__global__ void csr_fill_k(const int* __restrict__ ei, int* __restrict__ cursor,
                           unsigned short* __restrict__ col16) {
  int e = blockIdx.x * 256 + threadIdx.x;
  if (e < NE) {
    int pos = atomicAdd(&cursor[ei[NE + e]], 1);
    col16[pos] = (unsigned short)ei[e];
  }
}

// ---------------- prep: x relayout (fp32 chunked) + W^T hi/lo bf16 planes ----------------
// blocks [0, 3125): relayout; blocks [3125, 3509): wtprep (6 weights x 64 blocks).

__global__ __launch_bounds__(256) void prep_k(
    const float* __restrict__ x,
    const float* __restrict__ W0, const float* __restrict__ W1,
    const float* __restrict__ W2, const float* __restrict__ W3,
    const float* __restrict__ W4, const float* __restrict__ W5,
    float* __restrict__ xF, unsigned short* __restrict__ wt) {
  if (blockIdx.x < 3125) {
    // unit id = chunk*NN + node ; copy 64 B
    int unit = blockIdx.x * 256 + threadIdx.x;
    int c = unit / NN, node = unit - c * NN;
    const float4* src = reinterpret_cast<const float4*>(x + (size_t)node * DD + c * 16);
    float4* dst = reinterpret_cast<float4*>(xF + (size_t)unit * 16);
#pragma unroll
    for (int i = 0; i < 4; ++i) dst[i] = src[i];
  } else {
    int bb = blockIdx.x - 3125;
    int p = bb >> 6;
    const float* W = (p == 0) ? W0 : (p == 1) ? W1 : (p == 2) ? W2
                     : (p == 3) ? W3 : (p == 4) ? W4 : W5;
    unsigned short* thi = wt + (size_t)(2 * p) * 65536;
    unsigned short* tlo = wt + (size_t)(2 * p + 1) * 65536;
    int gid = (bb & 63) * 256 + threadIdx.x;  // 16384 = 256 n * 64 k-quads
    int n = gid >> 6, k4 = (gid & 63) << 2;
    ushort4 hi, lo;
    unsigned short* hp = &hi.x; unsigned short* lp = &lo.x;
#pragma unroll
    for (int r = 0; r < 4; ++r) {
      float v = W[(size_t)(k4 + r) * DD + n];
      unsigned short h = f2bf(v);
      hp[r] = h;
      lp[r] = f2bf(v - bf2f(h));
    }
    *reinterpret_cast<ushort4*>(thi + (size_t)n * DD + k4) = hi;
    *reinterpret_cast<ushort4*>(tlo + (size_t)n * DD + k4) = lo;
  }
}

// ---------------- aggregation: fp32, 4 lanes/node-chunk, serial edge walk ----------------
// Grid 12512 = 2 phases x 8 chunks x 782 node-groups. Block b -> XCD b%8 = chunk&7,
// so each chunk's 3.2 MB fp32 table is L2-resident on one XCD.

__global__ __launch_bounds__(256) void sage_agg_k(
    const float* __restrict__ act, const int* __restrict__ rp,
    const unsigned short* __restrict__ ci, const float* __restrict__ deg_inv,
    float* __restrict__ agg) {
  int b = blockIdx.x;
  int ph = (b >= 6256);
  int bb = ph ? b - 6256 : b;
  int c = ph * 8 + (bb & 7);
  int grp = bb >> 3;                       // 0..781
  int node = grp * 64 + (threadIdx.x >> 2);
  if (node >= NN) return;
  int q4 = (threadIdx.x & 3) * 4;          // this lane's 4 feats

  const float* base = act + (size_t)c * NN * 16;
  int beg = rp[node], end = rp[node + 1];

  f32x4 a0 = (f32x4)0.f, a1 = (f32x4)0.f;
  int e = beg;
  for (; e + 2 <= end; e += 2) {
    int s0 = (int)ci[e], s1 = (int)ci[e + 1];
    f32x4 v0 = *reinterpret_cast<const f32x4*>(base + (size_t)s0 * 16 + q4);
    f32x4 v1 = *reinterpret_cast<const f32x4*>(base + (size_t)s1 * 16 + q4);
    a0 += v0;
    a1 += v1;
  }
  if (e < end)
    a0 += *reinterpret_cast<const f32x4*>(base + (size_t)ci[e] * 16 + q4);
  a0 += a1;
  float di = deg_inv[node];
  a0 *= di;
  *reinterpret_cast<f32x4*>(agg + ((size_t)c * NN + node) * 16 + q4) = a0;
}

// ---------------- MFMA GEMM: 64x256 tile, BK=32, 8 waves, LDS-staged ----------------
// A (fp32 chunks) staged column-major per 1KB unit; in-register truncation hi/lo split.
// B = precomputed bf16 hi/lo W^T planes, fragment-linear. 3-product MFMA.

template <bool DO_BN>
__global__ __launch_bounds__(512) void sage_gemm_k(
    const float* __restrict__ aggF, const float* __restrict__ hF,
    const unsigned short* __restrict__ wlHi, const unsigned short* __restrict__ wlLo,
    const unsigned short* __restrict__ wrHi, const unsigned short* __restrict__ wrLo,
    const float* __restrict__ bias,
    const float* __restrict__ gamma, const float* __restrict__ beta,
    const float* __restrict__ mean, const float* __restrict__ var,
    float* __restrict__ outF, float* __restrict__ outC) {
  __shared__ __attribute__((aligned(128))) char lds[40960];  // A 8KB | B 32KB

  int tid = threadIdx.x, wave = tid >> 6, l = tid & 63;
  int lr = l & 15, lq = l >> 4;
  int sub = wave & 3, h = wave >> 2;
  int m0 = blockIdx.x * 64;

  f32x4 acc[8];
#pragma unroll
  for (int j = 0; j < 8; ++j) acc[j] = (f32x4)0.f;

#pragma unroll 1
  for (int t = 0; t < 16; ++t) {
    bool first = t < 8;
    const float* Ap = first ? aggF : hF;
    int t7 = t & 7;
    // ---- stage: 5 x 1KB units per wave (8 A + 32 B) ----
#pragma unroll
    for (int i = 0; i < 5; ++i) {
      int u = wave * 5 + i;
      if (u < 8) {
        // A unit u: chunk-half = u>>2, row-block = u&3; column-major 16B slots:
        // lane l -> row (l&15), slot (l>>4)
        int row = m0 + (u & 3) * 16 + (l & 15);
        row = row < NN ? row : NN - 1;
        gload_lds16(Ap + ((size_t)(2 * t7 + (u >> 2)) * NN + row) * 16 + (l >> 4) * 4,
                    &lds[u * 1024 + l * 16]);
      } else {
        int ub = u - 8, j = ub >> 1, p = ub & 1;
        const unsigned short* W = first ? (p ? wlLo : wlHi) : (p ? wrLo : wrHi);
        gload_lds16(W + (size_t)(j * 16 + (l & 15)) * DD + t7 * 32 + (l >> 4) * 8,
                    &lds[8192 + ub * 1024 + l * 16]);
      }
    }
    __syncthreads();
    // ---- A fragment: 8 f32 -> truncation hi/lo bf16 split ----
    int ua = (lq >> 1) * 4 + sub;
    int abase = ua * 1024 + (lq & 1) * 512 + lr * 16;
    f32x4 f0 = *reinterpret_cast<const f32x4*>(&lds[abase]);
    f32x4 f1 = *reinterpret_cast<const f32x4*>(&lds[abase + 256]);
    float af[8] = {f0[0], f0[1], f0[2], f0[3], f1[0], f1[1], f1[2], f1[3]};
    u32x4 hw, lw;
#pragma unroll
    for (int i = 0; i < 4; ++i) {
      uint32 b0 = __builtin_bit_cast(uint32, af[2 * i]);
      uint32 b1 = __builtin_bit_cast(uint32, af[2 * i + 1]);
      hw[i] = (b1 & 0xffff0000u) | (b0 >> 16);
      float l0 = af[2 * i] - __builtin_bit_cast(float, b0 & 0xffff0000u);
      float l1 = af[2 * i + 1] - __builtin_bit_cast(float, b1 & 0xffff0000u);
      lw[i] = (uint32)f2bf(l0) | ((uint32)f2bf(l1) << 16);
    }
    bf16x8s aH = __builtin_bit_cast(bf16x8s, hw);
    bf16x8s aL = __builtin_bit_cast(bf16x8s, lw);
    // ---- 8 n-frags x 3 products ----
#pragma unroll
    for (int jj = 0; jj < 8; ++jj) {
      int j = h * 8 + jj;
      bf16x8s bH = *reinterpret_cast<const bf16x8s*>(&lds[8192 + (j * 2 + 0) * 1024 + l * 16]);
      bf16x8s bL = *reinterpret_cast<const bf16x8s*>(&lds[8192 + (j * 2 + 1) * 1024 + l * 16]);
      mfma_bf16(aH, bH, acc[jj]);
      mfma_bf16(aH, bL, acc[jj]);
      mfma_bf16(aL, bH, acc[jj]);
    }
    __syncthreads();
  }

  // ---- epilogue: fragment layout matches fp32 chunk layout directly ----
#pragma unroll
  for (int jj = 0; jj < 8; ++jj) {
    int cj = h * 8 + jj;
    int n = cj * 16 + lr;
    float bb = bias[n], sc = 0.f, sh = 0.f;
    if (DO_BN) {
      float s = gamma[n] * rsqrtf(var[n] + EPSV);
      sc = s;
      sh = beta[n] - mean[n] * s;
    }
#pragma unroll
    for (int reg = 0; reg < 4; ++reg) {
      int m = m0 + sub * 16 + lq * 4 + reg;
      if (m < NN) {
        float v = acc[jj][reg] + bb;
        if (DO_BN) {
          size_t ui = ((size_t)cj * NN + m) * 16 + lr;
          v = fmaxf(v * sc + sh, 0.f) + hF[ui];  // BN+ReLU+residual (exact fp32)
          outC[ui] = v;
        } else {
          outF[(size_t)m * DD + n] = v;
        }
      }
    }
  }
}

// ---------------- launch ----------------

extern "C" void kernel_launch(void* const* d_in, const int* in_sizes, int n_in,
                              void* d_out, int out_size, void* d_ws, size_t ws_size,
                              hipStream_t stream) {
  const float* x   = (const float*)d_in[0];
  const int*   ei  = (const int*)d_in[1];
  const float* Wl[3] = {(const float*)d_in[2], (const float*)d_in[5], (const float*)d_in[8]};
  const float* Wr[3] = {(const float*)d_in[3], (const float*)d_in[6], (const float*)d_in[9]};
  const float* bs[3] = {(const float*)d_in[4], (const float*)d_in[7], (const float*)d_in[10]};
  const float* g0  = (const float*)d_in[11];
  const float* be0 = (const float*)d_in[12];
  const float* mu0 = (const float*)d_in[13];
  const float* va0 = (const float*)d_in[14];
  const float* g1  = (const float*)d_in[15];
  const float* be1 = (const float*)d_in[16];
  const float* mu1 = (const float*)d_in[17];
  const float* va1 = (const float*)d_in[18];
  float* out = (float*)d_out;

  char* w = (char*)d_ws;
  const size_t o_deg    = 0;
  const size_t o_rowptr = 262144;
  const size_t o_cursor = 524288;
  const size_t o_col16  = 786432;       // NE u16 = 1.6 MB
  const size_t o_deginv = 2621440;
  const size_t o_bsum   = 2883584;
  const size_t o_boff   = 2887680;
  const size_t o_wt     = 2891776;      // 12 planes * 131072 B
  const size_t ACT      = (size_t)16 * NN * 64;  // 51.2 MB fp32 chunked
  const size_t o_xF     = 6291456;
  const size_t o_h1F    = o_xF + ACT;
  const size_t o_aggF   = o_xF + 2 * ACT;        // end ~159.9 MB

  int*   deg     = (int*)(w + o_deg);
  int*   row_ptr = (int*)(w + o_rowptr);
  int*   cursor  = (int*)(w + o_cursor);
  unsigned short* col16 = (unsigned short*)(w + o_col16);
  float* deg_inv = (float*)(w + o_deginv);
  int*   bsum    = (int*)(w + o_bsum);
  int*   boff    = (int*)(w + o_boff);
  unsigned short* wt = (unsigned short*)(w + o_wt);
  float* xF   = (float*)(w + o_xF);
  float* h1F  = (float*)(w + o_h1F);
  float* aggF = (float*)(w + o_aggF);

  unsigned short* wlT[3][2];
  unsigned short* wrT[3][2];
  for (int l = 0; l < 3; ++l) {
    wlT[l][0] = wt + (size_t)(4 * l + 0) * 65536;
    wlT[l][1] = wt + (size_t)(4 * l + 1) * 65536;
    wrT[l][0] = wt + (size_t)(4 * l + 2) * 65536;
    wrT[l][1] = wt + (size_t)(4 * l + 3) * 65536;
  }

  const int SCAN_BLOCKS = (NN + 1023) / 1024;  // 49

  // ---- CSR build (6 dispatches) ----
  hipMemsetAsync(deg, 0, NN * sizeof(int), stream);
  deg_count_k<<<NE / 256, 256, 0, stream>>>(ei, deg);
  scan1_k<<<SCAN_BLOCKS, 1024, 0, stream>>>(deg, row_ptr, bsum);
  scan2_k<<<1, 64, 0, stream>>>(bsum, boff, row_ptr, SCAN_BLOCKS);
  scan3_k<<<SCAN_BLOCKS, 1024, 0, stream>>>(row_ptr, boff, deg, deg_inv, cursor);
  csr_fill_k<<<NE / 256, 256, 0, stream>>>(ei, cursor, col16);

  // ---- prep: x relayout + weight planes (1 dispatch) ----
  prep_k<<<3509, 256, 0, stream>>>(x, Wl[0], Wr[0], Wl[1], Wr[1], Wl[2], Wr[2], xF, wt);

  const int AGRID = 12512;           // 2 phases x 8 chunks x 782 groups (mult of 8)
  dim3 ggrid((NN + 63) / 64);        // 782

  // ---- layer 0: x -> h1 ----
  sage_agg_k<<<AGRID, 256, 0, stream>>>(xF, row_ptr, col16, deg_inv, aggF);
  sage_gemm_k<true><<<ggrid, 512, 0, stream>>>(
      aggF, xF, wlT[0][0], wlT[0][1], wrT[0][0], wrT[0][1],
      bs[0], g0, be0, mu0, va0, nullptr, h1F);
  // ---- layer 1: h1 -> h2 (into xF) ----
  sage_agg_k<<<AGRID, 256, 0, stream>>>(h1F, row_ptr, col16, deg_inv, aggF);
  sage_gemm_k<true><<<ggrid, 512, 0, stream>>>(
      aggF, h1F, wlT[1][0], wlT[1][1], wrT[1][0], wrT[1][1],
      bs[1], g1, be1, mu1, va1, nullptr, xF);
  // ---- layer 2: h2 -> out (fp32 row-major) ----
  sage_agg_k<<<AGRID, 256, 0, stream>>>(xF, row_ptr, col16, deg_inv, aggF);
  sage_gemm_k<false><<<ggrid, 512, 0, stream>>>(
      aggF, xF, wlT[2][0], wlT[2][1], wrT[2][0], wrT[2][1],
      bs[2], nullptr, nullptr, nullptr, nullptr, out, nullptr);
}